// Round 6
// baseline (928.713 us; speedup 1.0000x reference)
//
#include <hip/hip_runtime.h>
#include <hip/hip_bf16.h>
#include <math.h>

// GAT R6 = R5 + calibrated tail-spins so each kernel exceeds the 155us
// harness fills and appears in rocprof top-5 with its own counters.
//  k1  : Wh=x@W, w1/w2 logits, WhTt (32-col tiles)        [no spin]
//  k2a : adj(268MB) -> bitmask(8MB) via ballot            [+40000 ticks]
//  k2b : bits+WhTt -> masked-exp2 P -> MFMA P@Wh + Z      [+20000 ticks]
//  k3  : combine splits, /Z, +bias                        [+20000 ticks] (calibration: real work ~3us)

#define NN    8192
#define INF   256
#define OUTF  64
#define TILE1 16
#define ROWSB 4
#define K2AB  (NN / ROWSB)   // 2048
#define BM    64
#define SPL   8
#define CPS   (NN / SPL)     // 1024
#define KT    256
#define NSS   (CPS / KT)     // 4
#define BPR   128            // u64 words per bit-row
#define C0    1.0000900040501013f
#define LOG2E 1.4426950408889634f

typedef __bf16 bf16x8 __attribute__((ext_vector_type(8)));
typedef __bf16 bf16x4 __attribute__((ext_vector_type(4)));
typedef float  f32x4  __attribute__((ext_vector_type(4)));
typedef int    i32x4  __attribute__((ext_vector_type(4)));
typedef unsigned long long u64;

#if __has_builtin(__builtin_amdgcn_exp2f)
#define EXP2(x) __builtin_amdgcn_exp2f(x)
#else
#define EXP2(x) exp2f(x)
#endif

__device__ __forceinline__ void spin_ticks(long long ticks) {
    long long t0 = wall_clock64();
    while (wall_clock64() - t0 < ticks) { }
}

__device__ __forceinline__ __bf16 pcalc(unsigned m, float sv) {
    float el = fmaxf(sv, 0.2f * sv);
    float pe = EXP2(el);
    return (__bf16)(m ? pe : C0);
}

// k1: Wh = x@W; w1/w2=(Wh@a)*log2e; WhTt = bf16(Wh)^T tiled
__global__ __launch_bounds__(256) void k1_proj(
    const float* __restrict__ x, const float* __restrict__ W,
    const float* __restrict__ alpha,
    __bf16* __restrict__ WhTt, float* __restrict__ w1, float* __restrict__ w2)
{
    __shared__ float xs[TILE1 * INF];
    __shared__ float shwh[TILE1 * 65];
    const int tid = threadIdx.x;
    const int i0 = blockIdx.x * TILE1;

    const float4* xsrc = (const float4*)(x + (size_t)i0 * INF);
    float4* xdst = (float4*)xs;
#pragma unroll
    for (int it = 0; it < (TILE1 * INF / 4) / 256; ++it)
        xdst[tid + it * 256] = xsrc[tid + it * 256];
    __syncthreads();

    const int wave = tid >> 6, lane = tid & 63;
    const float a1 = alpha[lane], a2 = alpha[OUTF + lane];
    const int ilbase = wave * 4;

    float acc[4] = {};
#pragma unroll 4
    for (int k4 = 0; k4 < INF / 4; ++k4) {
        float wk0 = W[(4 * k4 + 0) * OUTF + lane];
        float wk1 = W[(4 * k4 + 1) * OUTF + lane];
        float wk2 = W[(4 * k4 + 2) * OUTF + lane];
        float wk3 = W[(4 * k4 + 3) * OUTF + lane];
#pragma unroll
        for (int rr = 0; rr < 4; ++rr) {
            float4 xv = *(const float4*)&xs[(ilbase + rr) * INF + 4 * k4];
            acc[rr] = fmaf(xv.x, wk0, acc[rr]);
            acc[rr] = fmaf(xv.y, wk1, acc[rr]);
            acc[rr] = fmaf(xv.z, wk2, acc[rr]);
            acc[rr] = fmaf(xv.w, wk3, acc[rr]);
        }
    }

#pragma unroll
    for (int rr = 0; rr < 4; ++rr) {
        const int il = ilbase + rr;
        const int i  = i0 + il;
        float a = acc[rr];
        float v1 = a * a1, v2 = a * a2;
#pragma unroll
        for (int off = 32; off > 0; off >>= 1) {
            v1 += __shfl_xor(v1, off);
            v2 += __shfl_xor(v2, off);
        }
        if (lane == 0) { w1[i] = v1 * LOG2E; w2[i] = v2 * LOG2E; }
        shwh[il * 65 + lane] = a;
    }
    __syncthreads();

#pragma unroll
    for (int it = 0; it < (OUTF * TILE1) / 256; ++it) {
        int idx = it * 256 + tid;
        int f = idx / TILE1, il = idx % TILE1;
        int j = i0 + il;
        WhTt[((size_t)(j >> 5) * 64 + f) * 32 + (j & 31)] = (__bf16)shwh[il * 65 + f];
    }
}

// k2a: adj -> bits, linear stream. +spin 40000 ticks.
__global__ __launch_bounds__(256) void k2a_bits(
    const int* __restrict__ adj, u64* __restrict__ bits)
{
    const int tid = threadIdx.x;
    const int wave = tid >> 6, lane = tid & 63;
    const int row = blockIdx.x * ROWSB + wave;
    const i32x4* ap = (const i32x4*)(adj + (size_t)row * NN);
    u64* brow = bits + (size_t)row * BPR;
#pragma unroll 4
    for (int c = 0; c < 32; ++c) {
        i32x4 a = __builtin_nontemporal_load(ap + c * 64 + lane);
        u64 b0 = __ballot(a[0] > 0);
        u64 b1 = __ballot(a[1] > 0);
        u64 b2 = __ballot(a[2] > 0);
        u64 b3 = __ballot(a[3] > 0);
        if (lane == 0) {
            ulonglong4 q; q.x = b0; q.y = b1; q.z = b2; q.w = b3;
            *(ulonglong4*)(brow + c * 4) = q;
        }
    }
    spin_ticks(40000);
}

// k2b: bits + tiled WhT -> P (LDS) -> 4 MFMA + Z-MFMA. +spin 20000 ticks.
__global__ __launch_bounds__(256) void k2b(
    const u64* __restrict__ bits, const float* __restrict__ w1g,
    const float* __restrict__ w2g, const __bf16* __restrict__ WhTt,
    float* __restrict__ pacc, float* __restrict__ pz)
{
    __shared__ __align__(16) char plds[4 * 16 * KT * 2];
    __shared__ float w2s[CPS];
    __shared__ float w1s[BM];
    const int tid = threadIdx.x;
    const int s  = blockIdx.x & (SPL - 1);
    const int row_tile = blockIdx.x >> 3;
    const int jb = s * CPS;

    ((float4*)w2s)[tid] = ((const float4*)(w2g + jb))[tid];
    if (tid < BM) w1s[tid] = w1g[row_tile * BM + tid];
    __syncthreads();

    const int wave = tid >> 6, lane = tid & 63;
    const int fl = lane & 15, g = lane >> 4;
    const int rw0 = row_tile * BM + wave * 16;

    f32x4 acc0 = {}, acc1 = {}, acc2 = {}, acc3 = {}, accZ = {};
    bf16x8 ones;
#pragma unroll
    for (int e = 0; e < 8; ++e) ones[e] = (__bf16)1.0f;

    char* pb = plds + wave * (16 * KT * 2);

    for (int ss = 0; ss < NSS; ++ss) {
        const int coff = ss * KT;
        const float4 wv = *(const float4*)(w2s + coff + 4 * lane);
        const u64* bchunk = bits + (size_t)rw0 * BPR + (s * 4 + ss) * 4;

#pragma unroll
        for (int r = 0; r < 16; ++r) {
            const float w1r = w1s[wave * 16 + r];
            const u64* bp = bchunk + (size_t)r * BPR;
            u64 b0 = bp[0], b1 = bp[1], b2 = bp[2], b3 = bp[3];
            bf16x4 pv;
            pv[0] = pcalc((unsigned)(b0 >> lane) & 1u, w1r + wv.x);
            pv[1] = pcalc((unsigned)(b1 >> lane) & 1u, w1r + wv.y);
            pv[2] = pcalc((unsigned)(b2 >> lane) & 1u, w1r + wv.z);
            pv[3] = pcalc((unsigned)(b3 >> lane) & 1u, w1r + wv.w);
            *(bf16x4*)(pb + r * (KT * 2) + ((lane * 8) ^ ((r & 7) << 4))) = pv;
        }

#pragma unroll
        for (int t = 0; t < KT / 32; ++t) {
            bf16x8 af = *(const bf16x8*)(
                pb + fl * (KT * 2) + (((t << 6) + (g << 4)) ^ ((fl & 7) << 4)));
            const __bf16* bt = WhTt + ((size_t)(jb + coff + 32 * t) >> 5) * (64 * 32)
                             + fl * 32 + g * 8;
            acc0 = __builtin_amdgcn_mfma_f32_16x16x32_bf16(af, *(const bf16x8*)(bt +    0), acc0, 0, 0, 0);
            acc1 = __builtin_amdgcn_mfma_f32_16x16x32_bf16(af, *(const bf16x8*)(bt +  512), acc1, 0, 0, 0);
            acc2 = __builtin_amdgcn_mfma_f32_16x16x32_bf16(af, *(const bf16x8*)(bt + 1024), acc2, 0, 0, 0);
            acc3 = __builtin_amdgcn_mfma_f32_16x16x32_bf16(af, *(const bf16x8*)(bt + 1536), acc3, 0, 0, 0);
            accZ = __builtin_amdgcn_mfma_f32_16x16x32_bf16(af, ones, accZ, 0, 0, 0);
        }
    }

    if (fl == 0) {
#pragma unroll
        for (int i = 0; i < 4; ++i)
            pz[(size_t)s * NN + rw0 + 4 * g + i] = accZ[i];
    }
    float* prow = pacc + ((size_t)s * NN + rw0 + 4 * g) * OUTF + fl;
#pragma unroll
    for (int i = 0; i < 4; ++i) {
        __builtin_nontemporal_store(acc0[i], prow + (size_t)i * OUTF + 0);
        __builtin_nontemporal_store(acc1[i], prow + (size_t)i * OUTF + 16);
        __builtin_nontemporal_store(acc2[i], prow + (size_t)i * OUTF + 32);
        __builtin_nontemporal_store(acc3[i], prow + (size_t)i * OUTF + 48);
    }
    spin_ticks(20000);
}

// k3: combine splits, /Z, +bias. +spin 20000 ticks (calibration kernel).
__global__ __launch_bounds__(256) void k3_final(
    const float* __restrict__ pacc, const float* __restrict__ pz,
    const float* __restrict__ bias, float* __restrict__ out)
{
    const int t = blockIdx.x * 256 + threadIdx.x;
    const int i = t >> 6, f = t & 63;
    float num = 0.f, z = 0.f;
#pragma unroll
    for (int s = 0; s < SPL; ++s) {
        num += pacc[(size_t)s * NN * OUTF + t];
        z   += pz[(size_t)s * NN + i];
    }
    out[t] = num / z + bias[f];
    spin_ticks(20000);
}

extern "C" void kernel_launch(void* const* d_in, const int* in_sizes, int n_in,
                              void* d_out, int out_size, void* d_ws, size_t ws_size,
                              hipStream_t stream)
{
    const float* x     = (const float*)d_in[0];
    const int*   adj   = (const int*)d_in[1];
    const float* W     = (const float*)d_in[2];
    const float* alpha = (const float*)d_in[3];
    const float* bias  = (const float*)d_in[4];
    float* out = (float*)d_out;

    char* ws = (char*)d_ws;
    size_t off = 0;
    __bf16* WhTt = (__bf16*)(ws + off); off += (size_t)NN * OUTF * 2;
    float* w1 = (float*)(ws + off); off += (size_t)NN * 4;
    float* w2 = (float*)(ws + off); off += (size_t)NN * 4;
    u64* bits = (u64*)(ws + off);   off += (size_t)NN * BPR * 8;
    float* pz   = (float*)(ws + off); off += (size_t)SPL * NN * 4;
    float* pacc = (float*)(ws + off); off += (size_t)SPL * NN * OUTF * 4;

    k1_proj<<<NN / TILE1, 256, 0, stream>>>(x, W, alpha, WhTt, w1, w2);
    k2a_bits<<<K2AB, 256, 0, stream>>>(adj, bits);
    k2b<<<(NN / BM) * SPL, 256, 0, stream>>>(bits, w1, w2, WhTt, pacc, pz);
    k3_final<<<(NN * OUTF) / 256, 256, 0, stream>>>(pacc, pz, bias, out);
}

// Round 7
// 729.121 us; speedup vs baseline: 1.2737x; 1.2737x over previous
//
#include <hip/hip_runtime.h>
#include <hip/hip_bf16.h>
#include <math.h>

// GAT R7 = R5 with a 600us spin ONLY in k2b so rocprof top-5 shows k2b's
// counters (R6 showed k2a=53.7us real, 5.0TB/s L3-assisted; k2b~55-60us is
// the unexplained elephant -> measure it before touching it).

#define NN    8192
#define INF   256
#define OUTF  64
#define TILE1 16
#define ROWSB 4
#define K2AB  (NN / ROWSB)   // 2048
#define BM    64
#define SPL   8
#define CPS   (NN / SPL)     // 1024
#define KT    256
#define NSS   (CPS / KT)     // 4
#define BPR   128            // u64 words per bit-row
#define C0    1.0000900040501013f
#define LOG2E 1.4426950408889634f

typedef __bf16 bf16x8 __attribute__((ext_vector_type(8)));
typedef __bf16 bf16x4 __attribute__((ext_vector_type(4)));
typedef float  f32x4  __attribute__((ext_vector_type(4)));
typedef int    i32x4  __attribute__((ext_vector_type(4)));
typedef unsigned long long u64;

#if __has_builtin(__builtin_amdgcn_exp2f)
#define EXP2(x) __builtin_amdgcn_exp2f(x)
#else
#define EXP2(x) exp2f(x)
#endif

__device__ __forceinline__ void spin_ticks(long long ticks) {
    long long t0 = wall_clock64();
    while (wall_clock64() - t0 < ticks) { }
}

__device__ __forceinline__ __bf16 pcalc(unsigned m, float sv) {
    float el = fmaxf(sv, 0.2f * sv);
    float pe = EXP2(el);
    return (__bf16)(m ? pe : C0);
}

// k1: Wh = x@W; w1/w2=(Wh@a)*log2e; WhTt = bf16(Wh)^T tiled
__global__ __launch_bounds__(256) void k1_proj(
    const float* __restrict__ x, const float* __restrict__ W,
    const float* __restrict__ alpha,
    __bf16* __restrict__ WhTt, float* __restrict__ w1, float* __restrict__ w2)
{
    __shared__ float xs[TILE1 * INF];
    __shared__ float shwh[TILE1 * 65];
    const int tid = threadIdx.x;
    const int i0 = blockIdx.x * TILE1;

    const float4* xsrc = (const float4*)(x + (size_t)i0 * INF);
    float4* xdst = (float4*)xs;
#pragma unroll
    for (int it = 0; it < (TILE1 * INF / 4) / 256; ++it)
        xdst[tid + it * 256] = xsrc[tid + it * 256];
    __syncthreads();

    const int wave = tid >> 6, lane = tid & 63;
    const float a1 = alpha[lane], a2 = alpha[OUTF + lane];
    const int ilbase = wave * 4;

    float acc[4] = {};
#pragma unroll 4
    for (int k4 = 0; k4 < INF / 4; ++k4) {
        float wk0 = W[(4 * k4 + 0) * OUTF + lane];
        float wk1 = W[(4 * k4 + 1) * OUTF + lane];
        float wk2 = W[(4 * k4 + 2) * OUTF + lane];
        float wk3 = W[(4 * k4 + 3) * OUTF + lane];
#pragma unroll
        for (int rr = 0; rr < 4; ++rr) {
            float4 xv = *(const float4*)&xs[(ilbase + rr) * INF + 4 * k4];
            acc[rr] = fmaf(xv.x, wk0, acc[rr]);
            acc[rr] = fmaf(xv.y, wk1, acc[rr]);
            acc[rr] = fmaf(xv.z, wk2, acc[rr]);
            acc[rr] = fmaf(xv.w, wk3, acc[rr]);
        }
    }

#pragma unroll
    for (int rr = 0; rr < 4; ++rr) {
        const int il = ilbase + rr;
        const int i  = i0 + il;
        float a = acc[rr];
        float v1 = a * a1, v2 = a * a2;
#pragma unroll
        for (int off = 32; off > 0; off >>= 1) {
            v1 += __shfl_xor(v1, off);
            v2 += __shfl_xor(v2, off);
        }
        if (lane == 0) { w1[i] = v1 * LOG2E; w2[i] = v2 * LOG2E; }
        shwh[il * 65 + lane] = a;
    }
    __syncthreads();

#pragma unroll
    for (int it = 0; it < (OUTF * TILE1) / 256; ++it) {
        int idx = it * 256 + tid;
        int f = idx / TILE1, il = idx % TILE1;
        int j = i0 + il;
        WhTt[((size_t)(j >> 5) * 64 + f) * 32 + (j & 31)] = (__bf16)shwh[il * 65 + f];
    }
}

// k2a: adj -> bits, linear stream (no spin; understood: ~54us, 5TB/s)
__global__ __launch_bounds__(256) void k2a_bits(
    const int* __restrict__ adj, u64* __restrict__ bits)
{
    const int tid = threadIdx.x;
    const int wave = tid >> 6, lane = tid & 63;
    const int row = blockIdx.x * ROWSB + wave;
    const i32x4* ap = (const i32x4*)(adj + (size_t)row * NN);
    u64* brow = bits + (size_t)row * BPR;
#pragma unroll 4
    for (int c = 0; c < 32; ++c) {
        i32x4 a = __builtin_nontemporal_load(ap + c * 64 + lane);
        u64 b0 = __ballot(a[0] > 0);
        u64 b1 = __ballot(a[1] > 0);
        u64 b2 = __ballot(a[2] > 0);
        u64 b3 = __ballot(a[3] > 0);
        if (lane == 0) {
            ulonglong4 q; q.x = b0; q.y = b1; q.z = b2; q.w = b3;
            *(ulonglong4*)(brow + c * 4) = q;
        }
    }
}

// k2b: bits + tiled WhT -> P (LDS) -> 4 MFMA + Z-MFMA. +spin 60000 ticks
// (measurement target: counters in top-5; real dur = shown - 600us)
__global__ __launch_bounds__(256) void k2b(
    const u64* __restrict__ bits, const float* __restrict__ w1g,
    const float* __restrict__ w2g, const __bf16* __restrict__ WhTt,
    float* __restrict__ pacc, float* __restrict__ pz)
{
    __shared__ __align__(16) char plds[4 * 16 * KT * 2];
    __shared__ float w2s[CPS];
    __shared__ float w1s[BM];
    const int tid = threadIdx.x;
    const int s  = blockIdx.x & (SPL - 1);
    const int row_tile = blockIdx.x >> 3;
    const int jb = s * CPS;

    ((float4*)w2s)[tid] = ((const float4*)(w2g + jb))[tid];
    if (tid < BM) w1s[tid] = w1g[row_tile * BM + tid];
    __syncthreads();

    const int wave = tid >> 6, lane = tid & 63;
    const int fl = lane & 15, g = lane >> 4;
    const int rw0 = row_tile * BM + wave * 16;

    f32x4 acc0 = {}, acc1 = {}, acc2 = {}, acc3 = {}, accZ = {};
    bf16x8 ones;
#pragma unroll
    for (int e = 0; e < 8; ++e) ones[e] = (__bf16)1.0f;

    char* pb = plds + wave * (16 * KT * 2);

    for (int ss = 0; ss < NSS; ++ss) {
        const int coff = ss * KT;
        const float4 wv = *(const float4*)(w2s + coff + 4 * lane);
        const u64* bchunk = bits + (size_t)rw0 * BPR + (s * 4 + ss) * 4;

#pragma unroll
        for (int r = 0; r < 16; ++r) {
            const float w1r = w1s[wave * 16 + r];
            const u64* bp = bchunk + (size_t)r * BPR;
            u64 b0 = bp[0], b1 = bp[1], b2 = bp[2], b3 = bp[3];
            bf16x4 pv;
            pv[0] = pcalc((unsigned)(b0 >> lane) & 1u, w1r + wv.x);
            pv[1] = pcalc((unsigned)(b1 >> lane) & 1u, w1r + wv.y);
            pv[2] = pcalc((unsigned)(b2 >> lane) & 1u, w1r + wv.z);
            pv[3] = pcalc((unsigned)(b3 >> lane) & 1u, w1r + wv.w);
            *(bf16x4*)(pb + r * (KT * 2) + ((lane * 8) ^ ((r & 7) << 4))) = pv;
        }

#pragma unroll
        for (int t = 0; t < KT / 32; ++t) {
            bf16x8 af = *(const bf16x8*)(
                pb + fl * (KT * 2) + (((t << 6) + (g << 4)) ^ ((fl & 7) << 4)));
            const __bf16* bt = WhTt + ((size_t)(jb + coff + 32 * t) >> 5) * (64 * 32)
                             + fl * 32 + g * 8;
            acc0 = __builtin_amdgcn_mfma_f32_16x16x32_bf16(af, *(const bf16x8*)(bt +    0), acc0, 0, 0, 0);
            acc1 = __builtin_amdgcn_mfma_f32_16x16x32_bf16(af, *(const bf16x8*)(bt +  512), acc1, 0, 0, 0);
            acc2 = __builtin_amdgcn_mfma_f32_16x16x32_bf16(af, *(const bf16x8*)(bt + 1024), acc2, 0, 0, 0);
            acc3 = __builtin_amdgcn_mfma_f32_16x16x32_bf16(af, *(const bf16x8*)(bt + 1536), acc3, 0, 0, 0);
            accZ = __builtin_amdgcn_mfma_f32_16x16x32_bf16(af, ones, accZ, 0, 0, 0);
        }
    }

    if (fl == 0) {
#pragma unroll
        for (int i = 0; i < 4; ++i)
            pz[(size_t)s * NN + rw0 + 4 * g + i] = accZ[i];
    }
    float* prow = pacc + ((size_t)s * NN + rw0 + 4 * g) * OUTF + fl;
#pragma unroll
    for (int i = 0; i < 4; ++i) {
        __builtin_nontemporal_store(acc0[i], prow + (size_t)i * OUTF + 0);
        __builtin_nontemporal_store(acc1[i], prow + (size_t)i * OUTF + 16);
        __builtin_nontemporal_store(acc2[i], prow + (size_t)i * OUTF + 32);
        __builtin_nontemporal_store(acc3[i], prow + (size_t)i * OUTF + 48);
    }
    spin_ticks(60000);
}

// k3: combine splits, /Z, +bias (no spin)
__global__ __launch_bounds__(256) void k3_final(
    const float* __restrict__ pacc, const float* __restrict__ pz,
    const float* __restrict__ bias, float* __restrict__ out)
{
    const int t = blockIdx.x * 256 + threadIdx.x;
    const int i = t >> 6, f = t & 63;
    float num = 0.f, z = 0.f;
#pragma unroll
    for (int s = 0; s < SPL; ++s) {
        num += pacc[(size_t)s * NN * OUTF + t];
        z   += pz[(size_t)s * NN + i];
    }
    out[t] = num / z + bias[f];
}

extern "C" void kernel_launch(void* const* d_in, const int* in_sizes, int n_in,
                              void* d_out, int out_size, void* d_ws, size_t ws_size,
                              hipStream_t stream)
{
    const float* x     = (const float*)d_in[0];
    const int*   adj   = (const int*)d_in[1];
    const float* W     = (const float*)d_in[2];
    const float* alpha = (const float*)d_in[3];
    const float* bias  = (const float*)d_in[4];
    float* out = (float*)d_out;

    char* ws = (char*)d_ws;
    size_t off = 0;
    __bf16* WhTt = (__bf16*)(ws + off); off += (size_t)NN * OUTF * 2;
    float* w1 = (float*)(ws + off); off += (size_t)NN * 4;
    float* w2 = (float*)(ws + off); off += (size_t)NN * 4;
    u64* bits = (u64*)(ws + off);   off += (size_t)NN * BPR * 8;
    float* pz   = (float*)(ws + off); off += (size_t)SPL * NN * 4;
    float* pacc = (float*)(ws + off); off += (size_t)SPL * NN * OUTF * 4;

    k1_proj<<<NN / TILE1, 256, 0, stream>>>(x, W, alpha, WhTt, w1, w2);
    k2a_bits<<<K2AB, 256, 0, stream>>>(adj, bits);
    k2b<<<(NN / BM) * SPL, 256, 0, stream>>>(bits, w1, w2, WhTt, pacc, pz);
    k3_final<<<(NN * OUTF) / 256, 256, 0, stream>>>(pacc, pz, bias, out);
}

// Round 8
// 111.415 us; speedup vs baseline: 8.3357x; 6.5442x over previous
//
#include <hip/hip_runtime.h>
#include <hip/hip_bf16.h>
#include <math.h>

// GAT: out = softmax(mask(lrelu(w1 + w2^T), adj)) @ (x@W) + bias
// R8: exp factorization + register-direct A-fragments.
//   P_ij = (w1_i + w2_j >= 0) ? e1_i*e2_j : f1_i*f2_j   (e=2^w, f=2^(0.2w))
//   masked -> 1.0 (bf16(exp(9e-5))). Lane (fl,g) of each wave computes its
//   own MFMA A-frag (row fl, cols 8g..8g+7) straight from adj (contiguous
//   32B/lane) — no bits pass, no P staging in LDS. 2048 blocks (8/CU).

#define NN    8192
#define INF   256
#define OUTF  64
#define TILE1 16
#define BM    64
#define C0    1.0000900040501013f   // expf(9e-5) -> bf16 1.0
#define LOG2E 1.4426950408889634f

typedef __bf16 bf16x8 __attribute__((ext_vector_type(8)));
typedef float  f32x4  __attribute__((ext_vector_type(4)));
typedef int    i32x4  __attribute__((ext_vector_type(4)));

// k1: Wh = x@W; per-row logit factors; WhTt = bf16(Wh)^T in 32-col tiles
__global__ __launch_bounds__(256) void k1_proj(
    const float* __restrict__ x, const float* __restrict__ W,
    const float* __restrict__ alpha, __bf16* __restrict__ WhTt,
    float* __restrict__ w1, float* __restrict__ e1, float* __restrict__ f1,
    float* __restrict__ w2, float* __restrict__ e2, float* __restrict__ f2)
{
    __shared__ float xs[TILE1 * INF];
    __shared__ float shwh[TILE1 * 65];
    const int tid = threadIdx.x;
    const int i0 = blockIdx.x * TILE1;

    const float4* xsrc = (const float4*)(x + (size_t)i0 * INF);
    float4* xdst = (float4*)xs;
#pragma unroll
    for (int it = 0; it < (TILE1 * INF / 4) / 256; ++it)
        xdst[tid + it * 256] = xsrc[tid + it * 256];
    __syncthreads();

    const int wave = tid >> 6, lane = tid & 63;
    const float a1 = alpha[lane], a2 = alpha[OUTF + lane];
    const int ilbase = wave * 4;

    float acc[4] = {};
#pragma unroll 4
    for (int k4 = 0; k4 < INF / 4; ++k4) {
        float wk0 = W[(4 * k4 + 0) * OUTF + lane];
        float wk1 = W[(4 * k4 + 1) * OUTF + lane];
        float wk2 = W[(4 * k4 + 2) * OUTF + lane];
        float wk3 = W[(4 * k4 + 3) * OUTF + lane];
#pragma unroll
        for (int rr = 0; rr < 4; ++rr) {
            float4 xv = *(const float4*)&xs[(ilbase + rr) * INF + 4 * k4];
            acc[rr] = fmaf(xv.x, wk0, acc[rr]);
            acc[rr] = fmaf(xv.y, wk1, acc[rr]);
            acc[rr] = fmaf(xv.z, wk2, acc[rr]);
            acc[rr] = fmaf(xv.w, wk3, acc[rr]);
        }
    }

#pragma unroll
    for (int rr = 0; rr < 4; ++rr) {
        const int il = ilbase + rr;
        const int i  = i0 + il;
        float a = acc[rr];
        float v1 = a * a1, v2 = a * a2;
#pragma unroll
        for (int off = 32; off > 0; off >>= 1) {
            v1 += __shfl_xor(v1, off);
            v2 += __shfl_xor(v2, off);
        }
        if (lane == 0) {
            float v1L = v1 * LOG2E, v2L = v2 * LOG2E;
            w1[i] = v1L; e1[i] = exp2f(v1L); f1[i] = exp2f(0.2f * v1L);
            w2[i] = v2L; e2[i] = exp2f(v2L); f2[i] = exp2f(0.2f * v2L);
        }
        shwh[il * 65 + lane] = a;
    }
    __syncthreads();

#pragma unroll
    for (int it = 0; it < (OUTF * TILE1) / 256; ++it) {
        int idx = it * 256 + tid;
        int f = idx / TILE1, il = idx % TILE1;
        int j = i0 + il;
        WhTt[((size_t)(j >> 5) * 64 + f) * 32 + (j & 31)] = (__bf16)shwh[il * 65 + f];
    }
}

// k2: stream adj directly into A-frags; P via factorized exp; 4+1 MFMAs.
template <int SPL>
__global__ __launch_bounds__(256) void k2_attn(
    const int* __restrict__ adj,
    const float* __restrict__ w1g, const float* __restrict__ e1g,
    const float* __restrict__ f1g, const float* __restrict__ w2g,
    const float* __restrict__ e2g, const float* __restrict__ f2g,
    const __bf16* __restrict__ WhTt, float* __restrict__ pacc,
    float* __restrict__ pz)
{
    constexpr int CPS = NN / SPL;
    __shared__ float nw2s[CPS], e2s[CPS], f2s[CPS];
    __shared__ float w1s[BM], e1s[BM], f1s[BM];
    const int tid = threadIdx.x;
    const int s = blockIdx.x % SPL;
    const int row_tile = blockIdx.x / SPL;
    const int jb = s * CPS;

    for (int i = tid; i < CPS; i += 256) {
        nw2s[i] = -w2g[jb + i];
        e2s[i]  =  e2g[jb + i];
        f2s[i]  =  f2g[jb + i];
    }
    if (tid < BM) {
        int r = row_tile * BM + tid;
        w1s[tid] = w1g[r]; e1s[tid] = e1g[r]; f1s[tid] = f1g[r];
    }
    __syncthreads();

    const int wave = tid >> 6, lane = tid & 63;
    const int fl = lane & 15, g = lane >> 4;
    const int rw0 = row_tile * BM + wave * 16;
    const int row = rw0 + fl;
    const float w1r = w1s[wave * 16 + fl];
    const float e1r = e1s[wave * 16 + fl];
    const float f1r = f1s[wave * 16 + fl];

    f32x4 acc0 = {}, acc1 = {}, acc2 = {}, acc3 = {}, accZ = {};
    bf16x8 ones;
#pragma unroll
    for (int e = 0; e < 8; ++e) ones[e] = (__bf16)1.0f;

    const i32x4* ap = (const i32x4*)(adj + (size_t)row * NN + jb + 8 * g);
    const __bf16* bb = WhTt + (size_t)(jb >> 5) * (64 * 32) + fl * 32 + g * 8;

#pragma unroll 2
    for (int t = 0; t < CPS / 32; ++t) {
        i32x4 a0 = __builtin_nontemporal_load(ap + 8 * t);
        i32x4 a1 = __builtin_nontemporal_load(ap + 8 * t + 1);
        const int co = 32 * t + 8 * g;
        float4 n0 = *(const float4*)(nw2s + co), n1 = *(const float4*)(nw2s + co + 4);
        float4 ee0 = *(const float4*)(e2s + co), ee1 = *(const float4*)(e2s + co + 4);
        float4 ff0 = *(const float4*)(f2s + co), ff1 = *(const float4*)(f2s + co + 4);

        int   ai[8] = {a0.x, a0.y, a0.z, a0.w, a1.x, a1.y, a1.z, a1.w};
        float nn[8] = {n0.x, n0.y, n0.z, n0.w, n1.x, n1.y, n1.z, n1.w};
        float ev[8] = {ee0.x, ee0.y, ee0.z, ee0.w, ee1.x, ee1.y, ee1.z, ee1.w};
        float fv[8] = {ff0.x, ff0.y, ff0.z, ff0.w, ff1.x, ff1.y, ff1.z, ff1.w};

        bf16x8 pa;
#pragma unroll
        for (int e = 0; e < 8; ++e) {
            bool pos = (w1r >= nn[e]);            // w1_i + w2_j >= 0
            float p = (pos ? e1r : f1r) * (pos ? ev[e] : fv[e]);
            p = (ai[e] > 0) ? p : C0;             // mask fill
            pa[e] = (__bf16)p;
        }

        const __bf16* bt = bb + (size_t)t * 2048;
        acc0 = __builtin_amdgcn_mfma_f32_16x16x32_bf16(pa, *(const bf16x8*)(bt +    0), acc0, 0, 0, 0);
        acc1 = __builtin_amdgcn_mfma_f32_16x16x32_bf16(pa, *(const bf16x8*)(bt +  512), acc1, 0, 0, 0);
        acc2 = __builtin_amdgcn_mfma_f32_16x16x32_bf16(pa, *(const bf16x8*)(bt + 1024), acc2, 0, 0, 0);
        acc3 = __builtin_amdgcn_mfma_f32_16x16x32_bf16(pa, *(const bf16x8*)(bt + 1536), acc3, 0, 0, 0);
        accZ = __builtin_amdgcn_mfma_f32_16x16x32_bf16(pa, ones, accZ, 0, 0, 0);
    }

    if (fl == 0) {
#pragma unroll
        for (int i = 0; i < 4; ++i)
            pz[(size_t)s * NN + rw0 + 4 * g + i] = accZ[i];
    }
    float* prow = pacc + ((size_t)s * NN + rw0 + 4 * g) * OUTF + fl;
#pragma unroll
    for (int i = 0; i < 4; ++i) {
        __builtin_nontemporal_store(acc0[i], prow + (size_t)i * OUTF + 0);
        __builtin_nontemporal_store(acc1[i], prow + (size_t)i * OUTF + 16);
        __builtin_nontemporal_store(acc2[i], prow + (size_t)i * OUTF + 32);
        __builtin_nontemporal_store(acc3[i], prow + (size_t)i * OUTF + 48);
    }
}

// k3: combine splits, divide by Z, add bias
template <int SPL>
__global__ __launch_bounds__(256) void k3_final(
    const float* __restrict__ pacc, const float* __restrict__ pz,
    const float* __restrict__ bias, float* __restrict__ out)
{
    const int t = blockIdx.x * 256 + threadIdx.x;
    const int i = t >> 6, f = t & 63;
    float num = 0.f, z = 0.f;
#pragma unroll
    for (int s = 0; s < SPL; ++s) {
        num += pacc[(size_t)s * NN * OUTF + t];
        z   += pz[(size_t)s * NN + i];
    }
    out[t] = num / z + bias[f];
}

extern "C" void kernel_launch(void* const* d_in, const int* in_sizes, int n_in,
                              void* d_out, int out_size, void* d_ws, size_t ws_size,
                              hipStream_t stream)
{
    const float* x     = (const float*)d_in[0];
    const int*   adj   = (const int*)d_in[1];
    const float* W     = (const float*)d_in[2];
    const float* alpha = (const float*)d_in[3];
    const float* bias  = (const float*)d_in[4];
    float* out = (float*)d_out;

    char* ws = (char*)d_ws;
    size_t off = 0;
    __bf16* WhTt = (__bf16*)(ws + off); off += (size_t)NN * OUTF * 2;
    float* w1 = (float*)(ws + off); off += (size_t)NN * 4;
    float* e1 = (float*)(ws + off); off += (size_t)NN * 4;
    float* f1 = (float*)(ws + off); off += (size_t)NN * 4;
    float* w2 = (float*)(ws + off); off += (size_t)NN * 4;
    float* e2 = (float*)(ws + off); off += (size_t)NN * 4;
    float* f2 = (float*)(ws + off); off += (size_t)NN * 4;

    const size_t need16 = off + (size_t)16 * NN * 4 + (size_t)16 * NN * OUTF * 4;
    const int split = (ws_size >= need16) ? 16 : 8;
    float* pz   = (float*)(ws + off); off += (size_t)split * NN * 4;
    float* pacc = (float*)(ws + off); off += (size_t)split * NN * OUTF * 4;

    k1_proj<<<NN / TILE1, 256, 0, stream>>>(x, W, alpha, WhTt, w1, e1, f1, w2, e2, f2);
    if (split == 16) {
        k2_attn<16><<<(NN / BM) * 16, 256, 0, stream>>>(adj, w1, e1, f1, w2, e2, f2, WhTt, pacc, pz);
        k3_final<16><<<(NN * OUTF) / 256, 256, 0, stream>>>(pacc, pz, bias, out);
    } else {
        k2_attn<8><<<(NN / BM) * 8, 256, 0, stream>>>(adj, w1, e1, f1, w2, e2, f2, WhTt, pacc, pz);
        k3_final<8><<<(NN * OUTF) / 256, 256, 0, stream>>>(pacc, pz, bias, out);
    }
}